// Round 2
// baseline (931.858 us; speedup 1.0000x reference)
//
#include <hip/hip_runtime.h>
#include <hip/hip_bf16.h>
#include <stdint.h>

#define H       256
#define INDIM   64
#define TSTEPS  128
#define BATCH   2048
#define MROWS   8
#define OUTD    4

typedef __attribute__((ext_vector_type(8))) short bf16x8;
typedef __attribute__((ext_vector_type(4))) float f32x4;

__device__ __forceinline__ short f2b(float x) {
  // fp32 -> bf16 round-to-nearest-even
  uint32_t u = __builtin_bit_cast(uint32_t, x);
  uint32_t r = (u + 0x7fffu + ((u >> 16) & 1u)) >> 16;
  return (short)(r & 0xffffu);
}

__device__ __forceinline__ float fast_tanh(float x) {
  float e = __expf(2.0f * x);
  return 1.0f - __fdividef(2.0f, e + 1.0f);
}

// Swizzled index into a [8][256] bf16 LDS tile (element index in shorts).
__device__ __forceinline__ int swz(int m, int n) {
  return (m * H + n) ^ ((m & 7) << 3);
}

// launch_bounds(512, 1): HIP/CUDA semantics = min 1 BLOCK per CU -> 8 waves/CU
// -> 2 waves/SIMD -> 256-VGPR budget. (512,2) forced 2 blocks/CU -> 128-VGPR
// cap -> spilled the 128 weight-fragment VGPRs to scratch (R1: 61MB WRITE_SIZE,
// 4400 cy/eval). Grid is exactly 256 blocks = 1/CU, so nothing is lost.
__global__ __launch_bounds__(512, 1) void node_kernel(
    const float* __restrict__ g_static, const float* __restrict__ g_times,
    const float* __restrict__ g_Win, const float* __restrict__ g_bin,
    const float* __restrict__ g_W1, const float* __restrict__ g_b1,
    const float* __restrict__ g_W2, const float* __restrict__ g_b2,
    const float* __restrict__ g_Wpk, const float* __restrict__ g_bpk,
    const float* __restrict__ g_Wpd, const float* __restrict__ g_bpd,
    float* __restrict__ g_out)
{
  __shared__ short arg_lds[MROWS * H];   // bf16 MFMA-A operand (current stage arg), swizzled
  __shared__ short h1_lds[MROWS * H];    // bf16 tanh intermediate, swizzled
  __shared__ float h_lds[MROWS * H];     // fp32 master h state
  __shared__ float s_lds[MROWS * INDIM]; // staged static_input rows
  __shared__ float t_lds[TSTEPS];        // staged times

  const int tid   = threadIdx.x;
  const int lane  = tid & 63;
  const int wid   = tid >> 6;       // 8 waves; wave owns N-cols [wid*32, wid*32+32)
  const int g     = lane >> 4;      // lane group 0..3
  const int c     = lane & 15;
  const int b0    = blockIdx.x * MROWS;
  const int ncol0 = wid * 32;
  const int am    = lane & 7;       // A-frag row: rows 8..15 duplicate 0..7 (broadcast reads)
  const bool upd  = (g < 2);        // lanes whose D rows (4g+r) are the 8 real rows
  const int dm    = 4 * g;          // D row base for upd lanes

  if (tid < TSTEPS) t_lds[tid] = g_times[tid];

  // ---- biases & projection weights (registers) ----
  const float b1v0 = g_b1[ncol0 + c];
  const float b1v1 = g_b1[ncol0 + 16 + c];
  const float b2v0 = g_b2[ncol0 + c];
  const float b2v1 = g_b2[ncol0 + 16 + c];
  const float bpk0 = g_bpk[0], bpk1 = g_bpk[1], bpk2 = g_bpk[2], bpk3 = g_bpk[3];
  const float bpdv = g_bpd[0];
  f32x4 wpk[4];
  float wpd[4];
#pragma unroll
  for (int j = 0; j < 4; ++j) {
    wpk[j] = *(const f32x4*)(g_Wpk + (lane + 64 * j) * 4);
    wpd[j] = g_Wpd[lane + 64 * j];
  }

  // ---- one-time: W1,W2 -> bf16 B-fragments, register-resident (128 VGPRs/lane) ----
  // B-frag for mfma 16x16x32: col n = lane&15, k = kt*32 + 8*(lane>>4) + u.
  bf16x8 w1f[8][2], w2f[8][2];
#pragma unroll
  for (int kt = 0; kt < 8; ++kt) {
#pragma unroll
    for (int nt = 0; nt < 2; ++nt) {
      const int n  = ncol0 + nt * 16 + c;
      const int kb = kt * 32 + g * 8;
      bf16x8 f1, f2;
#pragma unroll
      for (int u = 0; u < 8; ++u) {
        f1[u] = f2b(g_W1[(kb + u) * H + n]);
        f2[u] = f2b(g_W2[(kb + u) * H + n]);
      }
      w1f[kt][nt] = f1;
      w2f[kt][nt] = f2;
    }
  }

  // ---- h0 = static @ W_in + b_in ----
  {
    const int m = tid >> 6, k = tid & 63;
    s_lds[tid] = g_static[(b0 + m) * INDIM + k];
  }
  __syncthreads();
  {
    const int m  = tid >> 6;
    const int n0 = (tid & 63) * 4;
    float a0 = g_bin[n0], a1 = g_bin[n0 + 1], a2 = g_bin[n0 + 2], a3 = g_bin[n0 + 3];
#pragma unroll 8
    for (int k = 0; k < INDIM; ++k) {
      const float sv = s_lds[m * INDIM + k];
      const f32x4 w = *(const f32x4*)(g_Win + k * H + n0);
      a0 += sv * w[0]; a1 += sv * w[1]; a2 += sv * w[2]; a3 += sv * w[3];
    }
    h_lds[m * H + n0] = a0; h_lds[m * H + n0 + 1] = a1;
    h_lds[m * H + n0 + 2] = a2; h_lds[m * H + n0 + 3] = a3;
    arg_lds[swz(m, n0)]     = f2b(a0);
    arg_lds[swz(m, n0 + 1)] = f2b(a1);
    arg_lds[swz(m, n0 + 2)] = f2b(a2);
    arg_lds[swz(m, n0 + 3)] = f2b(a3);
  }
  __syncthreads();

  auto emit_pk = [&](int t) {
    float p0 = 0.f, p1 = 0.f, p2 = 0.f, p3 = 0.f;
#pragma unroll
    for (int j = 0; j < 4; ++j) {
      const float hv = h_lds[wid * H + lane + 64 * j];
      p0 += hv * wpk[j][0]; p1 += hv * wpk[j][1];
      p2 += hv * wpk[j][2]; p3 += hv * wpk[j][3];
    }
#pragma unroll
    for (int m = 1; m < 64; m <<= 1) {
      p0 += __shfl_xor(p0, m); p1 += __shfl_xor(p1, m);
      p2 += __shfl_xor(p2, m); p3 += __shfl_xor(p3, m);
    }
    if (lane == 0) {
      f32x4 res = {p0 + bpk0, p1 + bpk1, p2 + bpk2, p3 + bpk3};
      *(f32x4*)(g_out + ((size_t)(b0 + wid) * TSTEPS + t) * 4) = res;
    }
  };

  emit_pk(0);

  const float inv6 = 1.0f / 6.0f;
  for (int t = 1; t < TSTEPS; ++t) {
    const float dt = t_lds[t] - t_lds[t - 1];
    float hb[2][4];
    float ks[2][4];
    if (upd) {
#pragma unroll
      for (int nt = 0; nt < 2; ++nt)
#pragma unroll
        for (int r = 0; r < 4; ++r)
          hb[nt][r] = h_lds[(dm + r) * H + ncol0 + nt * 16 + c];
    }

#pragma unroll
    for (int ev = 0; ev < 4; ++ev) {
      // ---- matmul1: tanh-arg = arg @ W1 + b1 ----
      // Two half-K chains per N-frag: 4 independent depth-4 MFMA chains/wave,
      // so 8 chains per SIMD at 2 waves -> matrix pipe issue-bound, not
      // latency-serialized.
      f32x4 acc0a = {b1v0, b1v0, b1v0, b1v0};
      f32x4 acc1a = {b1v1, b1v1, b1v1, b1v1};
      f32x4 acc0b = {0.f, 0.f, 0.f, 0.f};
      f32x4 acc1b = {0.f, 0.f, 0.f, 0.f};
#pragma unroll
      for (int kt = 0; kt < 4; ++kt) {
        const bf16x8 aA = *(const bf16x8*)(arg_lds + swz(am, kt * 32 + g * 8));
        const bf16x8 aB = *(const bf16x8*)(arg_lds + swz(am, (kt + 4) * 32 + g * 8));
        acc0a = __builtin_amdgcn_mfma_f32_16x16x32_bf16(aA, w1f[kt][0], acc0a, 0, 0, 0);
        acc1a = __builtin_amdgcn_mfma_f32_16x16x32_bf16(aA, w1f[kt][1], acc1a, 0, 0, 0);
        acc0b = __builtin_amdgcn_mfma_f32_16x16x32_bf16(aB, w1f[kt + 4][0], acc0b, 0, 0, 0);
        acc1b = __builtin_amdgcn_mfma_f32_16x16x32_bf16(aB, w1f[kt + 4][1], acc1b, 0, 0, 0);
      }
      if (upd) {
#pragma unroll
        for (int r = 0; r < 4; ++r) {
          h1_lds[swz(dm + r, ncol0 + c)]      = f2b(fast_tanh(acc0a[r] + acc0b[r]));
          h1_lds[swz(dm + r, ncol0 + 16 + c)] = f2b(fast_tanh(acc1a[r] + acc1b[r]));
        }
      }
      __syncthreads();   // h1 ready; arg reads of this eval all complete

      // ---- matmul2: k = h1 @ W2 + b2 ----
      f32x4 k0a = {b2v0, b2v0, b2v0, b2v0};
      f32x4 k1a = {b2v1, b2v1, b2v1, b2v1};
      f32x4 k0b = {0.f, 0.f, 0.f, 0.f};
      f32x4 k1b = {0.f, 0.f, 0.f, 0.f};
#pragma unroll
      for (int kt = 0; kt < 4; ++kt) {
        const bf16x8 aA = *(const bf16x8*)(h1_lds + swz(am, kt * 32 + g * 8));
        const bf16x8 aB = *(const bf16x8*)(h1_lds + swz(am, (kt + 4) * 32 + g * 8));
        k0a = __builtin_amdgcn_mfma_f32_16x16x32_bf16(aA, w2f[kt][0], k0a, 0, 0, 0);
        k1a = __builtin_amdgcn_mfma_f32_16x16x32_bf16(aA, w2f[kt][1], k1a, 0, 0, 0);
        k0b = __builtin_amdgcn_mfma_f32_16x16x32_bf16(aB, w2f[kt + 4][0], k0b, 0, 0, 0);
        k1b = __builtin_amdgcn_mfma_f32_16x16x32_bf16(aB, w2f[kt + 4][1], k1b, 0, 0, 0);
      }
      if (upd) {
        float k0[4], k1[4];
#pragma unroll
        for (int r = 0; r < 4; ++r) {
          k0[r] = k0a[r] + k0b[r];
          k1[r] = k1a[r] + k1b[r];
        }
#pragma unroll
        for (int r = 0; r < 4; ++r) {
          if (ev == 0) { ks[0][r] = k0[r];            ks[1][r] = k1[r]; }
          else {
            const float wk = (ev == 3) ? 1.0f : 2.0f;
            ks[0][r] += wk * k0[r];  ks[1][r] += wk * k1[r];
          }
        }
        if (ev < 3) {
          const float cc = (ev == 2) ? dt : 0.5f * dt;
#pragma unroll
          for (int r = 0; r < 4; ++r) {
            arg_lds[swz(dm + r, ncol0 + c)]      = f2b(hb[0][r] + cc * k0[r]);
            arg_lds[swz(dm + r, ncol0 + 16 + c)] = f2b(hb[1][r] + cc * k1[r]);
          }
        } else {
          const float s6 = dt * inv6;
#pragma unroll
          for (int r = 0; r < 4; ++r) {
            const float hn0 = hb[0][r] + s6 * ks[0][r];
            const float hn1 = hb[1][r] + s6 * ks[1][r];
            h_lds[(dm + r) * H + ncol0 + c]      = hn0;
            h_lds[(dm + r) * H + ncol0 + 16 + c] = hn1;
            arg_lds[swz(dm + r, ncol0 + c)]      = f2b(hn0);
            arg_lds[swz(dm + r, ncol0 + 16 + c)] = f2b(hn1);
          }
        }
      }
      __syncthreads();   // arg (and, on ev3, h) ready for next eval/step
    }
    emit_pk(t);
  }

  // ---- pd = h_T @ W_pd + b_pd ----
  {
    float p = 0.0f;
#pragma unroll
    for (int j = 0; j < 4; ++j) p += h_lds[wid * H + lane + 64 * j] * wpd[j];
#pragma unroll
    for (int m = 1; m < 64; m <<= 1) p += __shfl_xor(p, m);
    if (lane == 0) g_out[(size_t)BATCH * TSTEPS * OUTD + b0 + wid] = p + bpdv;
  }
}

extern "C" void kernel_launch(void* const* d_in, const int* in_sizes, int n_in,
                              void* d_out, int out_size, void* d_ws, size_t ws_size,
                              hipStream_t stream) {
  const float* g_static = (const float*)d_in[0];
  const float* g_times  = (const float*)d_in[1];
  const float* g_Win    = (const float*)d_in[2];
  const float* g_bin    = (const float*)d_in[3];
  const float* g_W1     = (const float*)d_in[4];
  const float* g_b1     = (const float*)d_in[5];
  const float* g_W2     = (const float*)d_in[6];
  const float* g_b2     = (const float*)d_in[7];
  const float* g_Wpk    = (const float*)d_in[8];
  const float* g_bpk    = (const float*)d_in[9];
  const float* g_Wpd    = (const float*)d_in[10];
  const float* g_bpd    = (const float*)d_in[11];

  node_kernel<<<dim3(BATCH / MROWS), dim3(512), 0, stream>>>(
      g_static, g_times, g_Win, g_bin, g_W1, g_b1, g_W2, g_b2,
      g_Wpk, g_bpk, g_Wpd, g_bpd, (float*)d_out);
}

// Round 3
// 660.656 us; speedup vs baseline: 1.4105x; 1.4105x over previous
//
#include <hip/hip_runtime.h>
#include <hip/hip_bf16.h>
#include <stdint.h>

#define H       256
#define INDIM   64
#define TSTEPS  128
#define BATCH   2048
#define MROWS   8
#define OUTD    4

typedef __attribute__((ext_vector_type(8))) short bf16x8;
typedef __attribute__((ext_vector_type(4))) float f32x4;

__device__ __forceinline__ short b2s(float x) {
  __hip_bfloat16 h = __float2bfloat16(x);   // RNE; compiler pairs into v_cvt_pk_bf16_f32
  return __builtin_bit_cast(short, h);
}

// Swizzled index into a [8][256] bf16 LDS tile (element index in shorts).
__device__ __forceinline__ int swz(int m, int n) {
  return (m * H + n) ^ ((m & 7) << 3);
}

// lanes 0-31 keep a; lanes 32-63 receive b from (lane-32).
__device__ __forceinline__ float swap_hilo(float a, float b) {
#if __has_builtin(__builtin_amdgcn_permlane32_swap)
  typedef unsigned int u32x2 __attribute__((ext_vector_type(2)));
  u32x2 r = __builtin_amdgcn_permlane32_swap(
      __builtin_bit_cast(unsigned int, a),
      __builtin_bit_cast(unsigned int, b), false, false);
  return __builtin_bit_cast(float, r[0]);
#else
  float t = __shfl_xor(b, 32);
  return (threadIdx.x & 32) ? t : a;
#endif
}

// 512 threads = 8 waves MUST co-reside 2/SIMD, so HW forces <=256 unified
// regs/wave regardless; (512,1) just gives the allocator full freedom.
__global__ __launch_bounds__(512, 1) void node_kernel(
    const float* __restrict__ g_static, const float* __restrict__ g_times,
    const float* __restrict__ g_Win, const float* __restrict__ g_bin,
    const float* __restrict__ g_W1, const float* __restrict__ g_b1,
    const float* __restrict__ g_W2, const float* __restrict__ g_b2,
    const float* __restrict__ g_Wpk, const float* __restrict__ g_bpk,
    const float* __restrict__ g_Wpd, const float* __restrict__ g_bpd,
    float* __restrict__ g_out)
{
  __shared__ __align__(16) short arg_lds[MROWS * H];   // bf16 stage arg, swizzled
  __shared__ __align__(16) short h1_lds[MROWS * H];    // bf16 tanh intermediate, swizzled
  __shared__ __align__(16) short wpk_lds[8 * 64 * 8];  // Wpk B-fragments (8 kt)
  __shared__ float h_lds[MROWS * H];                   // fp32 h (init + final only)
  __shared__ float s_lds[MROWS * INDIM];
  __shared__ float t_lds[TSTEPS];

  const int tid   = threadIdx.x;
  const int lane  = tid & 63;
  const int wid   = tid >> 6;        // wave owns N-cols [wid*32, wid*32+32)
  const int g     = lane >> 4;       // 0..3
  const int c     = lane & 15;
  const int b0    = blockIdx.x * MROWS;
  const int ncol0 = wid * 32;
  const int am    = lane & 7;        // A-frag row (rows 8..15 broadcast-duplicate 0..7)
  const int gg    = (lane >> 4) & 1; // unified epilogue mapping: rows 4*gg+r
  const int hh    = lane >> 5;       //                           col 16*hh + c
  const int colu  = ncol0 + 16 * hh + c;
  const int dm    = 4 * g;

  if (tid < TSTEPS) t_lds[tid] = g_times[tid];

  // ---- per-lane constants ----
  const float b1u2 = 2.0f * g_b1[colu];   // tanh arg bias, pre-doubled
  const float b2u  = g_b2[colu];
  const float bpkc = g_bpk[c & 3];
  const float bpdv = g_bpd[0];
  float wpd[4];
#pragma unroll
  for (int j = 0; j < 4; ++j) wpd[j] = g_Wpd[lane + 64 * j];

  // ---- loop-invariant LDS addresses (element indices), register-resident ----
  int ra[8], wa[4], ha[4];
#pragma unroll
  for (int kt = 0; kt < 8; ++kt) ra[kt] = swz(am, kt * 32 + g * 8);
#pragma unroll
  for (int r = 0; r < 4; ++r) {
    wa[r] = swz(4 * gg + r, colu);
    ha[r] = (4 * gg + r) * H + colu;
  }

  // ---- W1,W2 -> bf16 B-fragments in registers (128 regs/lane) ----
  bf16x8 w1f[8][2], w2f[8][2];
#pragma unroll
  for (int kt = 0; kt < 8; ++kt) {
#pragma unroll
    for (int nt = 0; nt < 2; ++nt) {
      const int n  = ncol0 + nt * 16 + c;
      const int kb = kt * 32 + g * 8;
      bf16x8 f1, f2;
#pragma unroll
      for (int u = 0; u < 8; ++u) {
        f1[u] = b2s(g_W1[(kb + u) * H + n]);
        f2[u] = b2s(g_W2[(kb + u) * H + n]);
      }
      w1f[kt][nt] = f1;
      w2f[kt][nt] = f2;
    }
  }

  // ---- Wpk B-fragments -> LDS (wave 0; cols>=4 zero) ----
  if (wid == 0) {
#pragma unroll
    for (int kt = 0; kt < 8; ++kt) {
      bf16x8 f;
#pragma unroll
      for (int u = 0; u < 8; ++u) {
        const int k = kt * 32 + g * 8 + u;
        f[u] = (c < OUTD) ? b2s(g_Wpk[k * OUTD + c]) : (short)0;
      }
      *(bf16x8*)(wpk_lds + kt * 512 + lane * 8) = f;
    }
  }

  // ---- h0 = static @ W_in + b_in ----
  s_lds[tid] = g_static[(b0 + (tid >> 6)) * INDIM + (tid & 63)];
  __syncthreads();
  {
    const int m  = tid >> 6;
    const int n0 = (tid & 63) * 4;
    float a0 = g_bin[n0], a1 = g_bin[n0 + 1], a2 = g_bin[n0 + 2], a3 = g_bin[n0 + 3];
#pragma unroll 8
    for (int k = 0; k < INDIM; ++k) {
      const float sv = s_lds[m * INDIM + k];
      const f32x4 w = *(const f32x4*)(g_Win + k * H + n0);
      a0 += sv * w[0]; a1 += sv * w[1]; a2 += sv * w[2]; a3 += sv * w[3];
    }
    h_lds[m * H + n0] = a0;     h_lds[m * H + n0 + 1] = a1;
    h_lds[m * H + n0 + 2] = a2; h_lds[m * H + n0 + 3] = a3;
    arg_lds[swz(m, n0)]     = b2s(a0);
    arg_lds[swz(m, n0 + 1)] = b2s(a1);
    arg_lds[swz(m, n0 + 2)] = b2s(a2);
    arg_lds[swz(m, n0 + 3)] = b2s(a3);
  }
  __syncthreads();

  // ---- h state lives in registers from here on ----
  float hb[4];
#pragma unroll
  for (int r = 0; r < 4; ++r) hb[r] = h_lds[ha[r]];

  // pk_t = bf16(h_t) @ Wpk + b_pk, one wave, 8 MFMAs. arg_lds holds bf16(h_t)
  // right after ev3 (and after init). Safe vs next-step arg overwrite: that
  // write is behind a barrier wave 0 hasn't reached yet.
  auto emit_pk = [&](int t) {
    if (wid == 0) {
      f32x4 acc = {0.f, 0.f, 0.f, 0.f};
#pragma unroll
      for (int kt = 0; kt < 8; ++kt) {
        const bf16x8 aA = *(const bf16x8*)(arg_lds + ra[kt]);
        const bf16x8 bW = *(const bf16x8*)(wpk_lds + kt * 512 + lane * 8);
        acc = __builtin_amdgcn_mfma_f32_16x16x32_bf16(aA, bW, acc, 0, 0, 0);
      }
      if (g < 2 && c < OUTD) {
#pragma unroll
        for (int r = 0; r < 4; ++r)
          g_out[((size_t)(b0 + dm + r) * TSTEPS + t) * OUTD + c] = acc[r] + bpkc;
      }
    }
  };

  emit_pk(0);

  for (int t = 1; t < TSTEPS; ++t) {
    const float dt = t_lds[t] - t_lds[t - 1];
    const float s6 = dt * (1.0f / 6.0f);
    float ks[4];

#pragma unroll
    for (int ev = 0; ev < 4; ++ev) {
      // ---- phase 1: h1 = tanh(arg @ W1 + b1) ----
      f32x4 A0 = {0.f,0.f,0.f,0.f}, A1 = {0.f,0.f,0.f,0.f};
      f32x4 B0 = {0.f,0.f,0.f,0.f}, B1 = {0.f,0.f,0.f,0.f};
#pragma unroll
      for (int kt = 0; kt < 4; ++kt) {
        const bf16x8 aA = *(const bf16x8*)(arg_lds + ra[kt]);
        const bf16x8 aB = *(const bf16x8*)(arg_lds + ra[kt + 4]);
        A0 = __builtin_amdgcn_mfma_f32_16x16x32_bf16(aA, w1f[kt][0], A0, 0, 0, 0);
        A1 = __builtin_amdgcn_mfma_f32_16x16x32_bf16(aA, w1f[kt][1], A1, 0, 0, 0);
        B0 = __builtin_amdgcn_mfma_f32_16x16x32_bf16(aB, w1f[kt + 4][0], B0, 0, 0, 0);
        B1 = __builtin_amdgcn_mfma_f32_16x16x32_bf16(aB, w1f[kt + 4][1], B1, 0, 0, 0);
      }
#pragma unroll
      for (int r = 0; r < 4; ++r) {
        const float v = swap_hilo(A0[r] + B0[r], A1[r] + B1[r]); // all-lane, 4 elems/lane
        const float e = __expf(__builtin_fmaf(2.0f, v, b1u2));   // exp(2(v+b1))
        const float th = 1.0f - __fdividef(2.0f, e + 1.0f);
        h1_lds[wa[r]] = b2s(th);
      }
      __syncthreads();

      // ---- phase 2: k = h1 @ W2 + b2, RK4 update ----
      A0 = f32x4{0.f,0.f,0.f,0.f}; A1 = f32x4{0.f,0.f,0.f,0.f};
      B0 = f32x4{0.f,0.f,0.f,0.f}; B1 = f32x4{0.f,0.f,0.f,0.f};
#pragma unroll
      for (int kt = 0; kt < 4; ++kt) {
        const bf16x8 aA = *(const bf16x8*)(h1_lds + ra[kt]);
        const bf16x8 aB = *(const bf16x8*)(h1_lds + ra[kt + 4]);
        A0 = __builtin_amdgcn_mfma_f32_16x16x32_bf16(aA, w2f[kt][0], A0, 0, 0, 0);
        A1 = __builtin_amdgcn_mfma_f32_16x16x32_bf16(aA, w2f[kt][1], A1, 0, 0, 0);
        B0 = __builtin_amdgcn_mfma_f32_16x16x32_bf16(aB, w2f[kt + 4][0], B0, 0, 0, 0);
        B1 = __builtin_amdgcn_mfma_f32_16x16x32_bf16(aB, w2f[kt + 4][1], B1, 0, 0, 0);
      }
#pragma unroll
      for (int r = 0; r < 4; ++r) {
        const float kv = swap_hilo(A0[r] + B0[r], A1[r] + B1[r]) + b2u;
        if (ev == 0)      ks[r] = kv;
        else if (ev == 3) ks[r] += kv;
        else              ks[r] += 2.0f * kv;
        if (ev < 3) {
          const float cc = (ev == 2) ? dt : 0.5f * dt;
          arg_lds[wa[r]] = b2s(__builtin_fmaf(cc, kv, hb[r]));
        } else {
          hb[r] = __builtin_fmaf(s6, ks[r], hb[r]);
          arg_lds[wa[r]] = b2s(hb[r]);
        }
      }
      __syncthreads();
    }
    emit_pk(t);
  }

  // ---- pd = h_T @ W_pd + b_pd ----
#pragma unroll
  for (int r = 0; r < 4; ++r) h_lds[ha[r]] = hb[r];
  __syncthreads();
  {
    float p = 0.0f;
#pragma unroll
    for (int j = 0; j < 4; ++j) p += h_lds[wid * H + lane + 64 * j] * wpd[j];
#pragma unroll
    for (int m = 1; m < 64; m <<= 1) p += __shfl_xor(p, m);
    if (lane == 0) g_out[(size_t)BATCH * TSTEPS * OUTD + b0 + wid] = p + bpdv;
  }
}

extern "C" void kernel_launch(void* const* d_in, const int* in_sizes, int n_in,
                              void* d_out, int out_size, void* d_ws, size_t ws_size,
                              hipStream_t stream) {
  const float* g_static = (const float*)d_in[0];
  const float* g_times  = (const float*)d_in[1];
  const float* g_Win    = (const float*)d_in[2];
  const float* g_bin    = (const float*)d_in[3];
  const float* g_W1     = (const float*)d_in[4];
  const float* g_b1     = (const float*)d_in[5];
  const float* g_W2     = (const float*)d_in[6];
  const float* g_b2     = (const float*)d_in[7];
  const float* g_Wpk    = (const float*)d_in[8];
  const float* g_bpk    = (const float*)d_in[9];
  const float* g_Wpd    = (const float*)d_in[10];
  const float* g_bpd    = (const float*)d_in[11];

  node_kernel<<<dim3(BATCH / MROWS), dim3(512), 0, stream>>>(
      g_static, g_times, g_Win, g_bin, g_W1, g_b1, g_W2, g_b2,
      g_Wpk, g_bpk, g_Wpd, g_bpd, (float*)d_out);
}